// Round 24
// baseline (54.316 us; speedup 1.0000x reference)
//
#include <hip/hip_runtime.h>
#include <hip/hip_bf16.h>

#define BATCH 8
#define CIN   64
#define COUT  64
#define HH    128
#define WW    128
#define HW    (HH * WW)
#define OFFC  18
#define KK    9
#define NROWS 12
#define SPX   36                  // staged columns: 32 + 2 halo each side
#define ROWB2 (SPX * 128)         // 4608 B per staged row

typedef __attribute__((ext_vector_type(8))) _Float16 half8;
typedef __attribute__((ext_vector_type(8))) unsigned short ushort8;
typedef __attribute__((ext_vector_type(4))) float f32x4;

__device__ __forceinline__ unsigned short f2hbits(float v) {
    _Float16 h = (_Float16)v;
    return __builtin_bit_cast(unsigned short, h);
}
__device__ __forceinline__ half8 splat8(float f) {
    _Float16 h = (_Float16)f;
    return (half8){h, h, h, h, h, h, h, h};
}

// ------- Kernel X: x (b,c,h,w) f32 -> xT (b,h,w,c) f16 -------
__global__ __launch_bounds__(256) void to_chlast_k(
    const float* __restrict__ x, unsigned short* __restrict__ xT)
{
    __shared__ unsigned short t[128 * 72];
    int blk = blockIdx.x;                    // ho*8 + b
    int b  = blk & 7;
    int ho = blk >> 3;
    int tid = threadIdx.x;

    const float* xr = x + (size_t)b * CIN * HW + ho * WW;
    for (int i = tid; i < 2048; i += 256) {
        int c = i >> 5, w4 = (i & 31) * 4;
        float4 v = *(const float4*)(xr + (size_t)c * HW + w4);
        t[(w4 + 0) * 72 + c] = f2hbits(v.x);
        t[(w4 + 1) * 72 + c] = f2hbits(v.y);
        t[(w4 + 2) * 72 + c] = f2hbits(v.z);
        t[(w4 + 3) * 72 + c] = f2hbits(v.w);
    }
    __syncthreads();

    unsigned short* orow = xT + (size_t)(b * HH + ho) * WW * 64;
    for (int j = tid; j < 1024; j += 256) {
        int w = j >> 3, c8 = (j & 7) * 8;
        *(ushort8*)(orow + w * 64 + c8) = *(const ushort8*)(t + w * 72 + c8);
    }
}

// ------- Kernel B (merged): w_deform -> wf frags; w_offset -> wfo frags (f16) -------
__global__ __launch_bounds__(256) void build_w_k(
    const float* __restrict__ wd, const float* __restrict__ wo,
    unsigned short* __restrict__ wf, unsigned short* __restrict__ wfo)
{
    int idx = blockIdx.x * 256 + threadIdx.x;
    if (idx < 36864) {                               // wf: o*576 + ck
        int ck = idx % 576;
        int o  = idx / 576;
        int c = ck & 63, k = ck >> 6;
        float v = wd[o * 576 + c * 9 + k];
        int kk = ck >> 5, nt = o >> 4;
        int lane = (o & 15) | (((ck >> 3) & 3) << 4);
        int j = ck & 7;
        wf[((kk * 4 + nt) * 64 + lane) * 8 + j] = f2hbits(v);
    } else if (idx < 36864 + 18432) {                // wfo: ov*576 + ck, N pad 18->32
        int i2 = idx - 36864;
        int ck = i2 % 576;
        int ov = i2 / 576;
        int c = ck & 63, tap = ck >> 6;
        float v = (ov < OFFC) ? wo[ov * 576 + c * 9 + tap] : 0.f;
        int kk = ck >> 5, nt = ov >> 4;
        int lane = (ov & 15) | (((ck >> 3) & 3) << 4);
        int j = ck & 7;
        wfo[((kk * 2 + nt) * 64 + lane) * 8 + j] = f2hbits(v);
    }
}

// ---------- Kernel C: LDS-staged gather, 8-row x 32-px / 1024-thr, 2 blocks/CU ----------
// Max-occupancy end-point of the TLP axis: 16 waves/block, stage = 12 rows x 36
// cols = 55.3KB + offsL 20.5KB = 75.8KB -> 2 blocks/CU -> 8 waves/SIMD (max),
// grid = 16 x 4 x 8 = 512 = exactly 2/CU, ONE round, no ragged tail. Stage
// redundancy 1.5 staged-rows/output-row (vs 2.25 in R23). Datapath byte-identical
// to verified R16/R23 (packed-f16 interp, pre-masked weights, bit-identical
// fallback). VGPR ~60 <= 64 keeps 8 waves/SIMD legal; launch_bounds leaves the
// allocator free (R6 lesson: hard caps kill ILP).
__global__ __launch_bounds__(1024, 4) void deform_fusedE_k(
    const unsigned short* __restrict__ xT,
    const half8* __restrict__ wfo,
    const half8* __restrict__ wf, float* __restrict__ out)
{
    __shared__ char  stage[NROWS * ROWB2];  // 55296 B
    __shared__ float offsL[16][16 * 20];    // 20480 B  (total 75776 B)

    int tid  = threadIdx.x;
    int blk  = blockIdx.x;                  // (grp*4+wseg)*8 + b
    int b    = blk & 7;
    int t2   = blk >> 3;
    int wseg = t2 & 3;
    int ho0  = (t2 >> 2) * 8;               // 8 rows per block
    int row_lo = ho0 - 2;                   // staged rows row_lo .. row_lo+11
    int wo0  = wseg * 32;
    int col_lo = wo0 - 2;                   // staged cols col_lo .. col_lo+35

    const unsigned short* pT = xT + (size_t)b * HW * 64;

    int lane  = tid & 63;
    int wave  = tid >> 6;                   // 0..15
    int wl    = wave & 1;                   // px half
    int ho    = ho0 + (wave >> 1);          // this wave's output row (8 rows x 2 halves)
    int prow  = lane & 15;
    int khalf = lane >> 4;
    int px    = wo0 + wl * 16 + prow;       // this lane's pixel (absolute)

    // ---- STAGE: 12 rows x 36 cols of xT[b] -> swizzled LDS (1024 threads) ----
    for (int c = tid; c < NROWS * SPX * 8; c += 1024) {
        int r    = c / (SPX * 8);
        int rem  = c - r * (SPX * 8);
        int xs   = rem >> 3;
        int slot = rem & 7;
        int ar = row_lo + r, ac = col_lo + xs;
        if ((unsigned)ar < (unsigned)HH && (unsigned)ac < (unsigned)WW) {
            ushort8 v = *(const ushort8*)(pT + (((size_t)ar * WW + ac) << 6) + slot * 8);
            *(ushort8*)(stage + r * ROWB2 + xs * 128 + ((slot ^ (xs & 7)) << 4)) = v;
        }
    }
    __syncthreads();

    auto LRD = [&](int r, int xs, int slot) -> half8 {
        return *(const half8*)(stage + r * ROWB2 + xs * 128 + ((slot ^ (xs & 7)) << 4));
    };
    auto GRD = [&](int idx, int h) -> half8 {
        return *(const half8*)(pT + ((size_t)idx << 6) + (khalf << 3) + h * 32);
    };

    // ---- phase A: offsets conv via MFMA (f16) from the stage ----
    {
        f32x4 oa0 = {0.f,0.f,0.f,0.f}, oa1 = {0.f,0.f,0.f,0.f};
        #pragma unroll
        for (int kk = 0; kk < 18; ++kk) {
            int tap = kk >> 1;
            int y   = ho + tap / 3 - 1;            // in [ho0-1, ho0+8], always staged
            int dx  = tap % 3 - 1;
            int slot = khalf + (kk & 1) * 4;
            half8 a0 = {0,0,0,0,0,0,0,0};
            int xw = px + dx;
            if ((unsigned)y < HH && (unsigned)xw < WW) {
                a0 = LRD(y - row_lo, xw - col_lo, slot);   // ry in [1,10], xs in [1,34]
            }
            half8 b0 = wfo[(kk * 2 + 0) * 64 + lane];
            half8 b1 = wfo[(kk * 2 + 1) * 64 + lane];
            oa0 = __builtin_amdgcn_mfma_f32_16x16x32_f16(a0, b0, oa0, 0, 0, 0);
            oa1 = __builtin_amdgcn_mfma_f32_16x16x32_f16(a0, b1, oa1, 0, 0, 0);
        }
        int ocol = lane & 15;
        int pl0  = khalf * 4;
        #pragma unroll
        for (int r = 0; r < 4; ++r)
            offsL[wave][(pl0 + r) * 20 + ocol] = oa0[r];
        if (ocol < 2) {
            #pragma unroll
            for (int r = 0; r < 4; ++r)
                offsL[wave][(pl0 + r) * 20 + 16 + ocol] = oa1[r];
        }
    }
    // no barrier: offsL slice is wave-private

    // ---- tap loop: inline positions + LDS gather + packed-f16 interp + MFMA ----
    f32x4 acc0 = {0.f,0.f,0.f,0.f}, acc1 = {0.f,0.f,0.f,0.f};
    f32x4 acc2 = {0.f,0.f,0.f,0.f}, acc3 = {0.f,0.f,0.f,0.f};

    #pragma unroll
    for (int t = 0; t < 9; ++t) {
        half8 b00 = wf[((2 * t) * 4 + 0) * 64 + lane];
        half8 b01 = wf[((2 * t) * 4 + 1) * 64 + lane];
        half8 b02 = wf[((2 * t) * 4 + 2) * 64 + lane];
        half8 b03 = wf[((2 * t) * 4 + 3) * 64 + lane];
        half8 b10 = wf[((2 * t + 1) * 4 + 0) * 64 + lane];
        half8 b11 = wf[((2 * t + 1) * 4 + 1) * 64 + lane];
        half8 b12 = wf[((2 * t + 1) * 4 + 2) * 64 + lane];
        half8 b13 = wf[((2 * t + 1) * 4 + 3) * 64 + lane];

        // ---------- positions ----------
        float dy = offsL[wave][prow * 20 + 2 * t];
        float dx = offsL[wave][prow * 20 + 2 * t + 1];
        float yy = (float)(ho - 1 + t / 3) + dy;
        float xx = (float)(px - 1 + t % 3) + dx;
        float y0 = floorf(yy), x0 = floorf(xx);
        float wy1 = yy - y0, wx1 = xx - x0;
        float wy0 = 1.f - wy1, wx0 = 1.f - wx1;
        bool vv = (yy > -1.f) && (yy < (float)HH) && (xx > -1.f) && (xx < (float)WW);
        int y0i = (int)y0, x0i = (int)x0;
        bool iy0 = (unsigned)y0i < HH, iy1 = (unsigned)(y0i + 1) < HH;
        bool ix0 = (unsigned)x0i < WW, ix1 = (unsigned)(x0i + 1) < WW;
        float w00 = wy0 * wx0 * ((vv && iy0 && ix0) ? 1.f : 0.f);
        float w01 = wy0 * wx1 * ((vv && iy0 && ix1) ? 1.f : 0.f);
        float w10 = wy1 * wx0 * ((vv && iy1 && ix0) ? 1.f : 0.f);
        float w11 = wy1 * wx1 * ((vv && iy1 && ix1) ? 1.f : 0.f);
        int yc0 = min(max(y0i, 0), HH - 1), yc1 = min(max(y0i + 1, 0), HH - 1);
        int xc0 = min(max(x0i, 0), WW - 1), xc1 = min(max(x0i + 1, 0), WW - 1);

        // ---------- stage coords + in-stage tests ----------
        int ry0 = yc0 - row_lo, ry1 = yc1 - row_lo;
        int xs0 = xc0 - col_lo, xs1 = xc1 - col_lo;
        int r0 = min(max(ry0, 0), NROWS - 1), r1 = min(max(ry1, 0), NROWS - 1);
        int s0 = min(max(xs0, 0), SPX - 1),   s1 = min(max(xs1, 0), SPX - 1);
        bool colOOT = ((unsigned)xs0 >= (unsigned)SPX) || ((unsigned)xs1 >= (unsigned)SPX);
        bool bad0 = ((unsigned)ry0 >= (unsigned)NROWS) || colOOT;
        bool bad1 = ((unsigned)ry1 >= (unsigned)NROWS) || colOOT;

        // ---------- LDS gathers (ds_read_b128) ----------
        half8 C0a = LRD(r0, s0, khalf),     C0b = LRD(r0, s0, khalf + 4);
        half8 C1a = LRD(r0, s1, khalf),     C1b = LRD(r0, s1, khalf + 4);
        half8 C2a = LRD(r1, s0, khalf),     C2b = LRD(r1, s0, khalf + 4);
        half8 C3a = LRD(r1, s1, khalf),     C3b = LRD(r1, s1, khalf + 4);

        // ---------- rare out-of-stage fallbacks (same bytes from global) ----------
        if (bad0) {
            C0a = GRD(yc0 * WW + xc0, 0);  C0b = GRD(yc0 * WW + xc0, 1);
            C1a = GRD(yc0 * WW + xc1, 0);  C1b = GRD(yc0 * WW + xc1, 1);
        }
        if (bad1) {
            C2a = GRD(yc1 * WW + xc0, 0);  C2b = GRD(yc1 * WW + xc0, 1);
            C3a = GRD(yc1 * WW + xc1, 0);  C3b = GRD(yc1 * WW + xc1, 1);
        }

        // ---------- packed-f16 interp: result IS the MFMA fragment ----------
        half8 s00 = splat8(w00), s01 = splat8(w01), s10 = splat8(w10), s11 = splat8(w11);
        half8 a0 = C0a * s00 + C1a * s01 + C2a * s10 + C3a * s11;
        half8 a1 = C0b * s00 + C1b * s01 + C2b * s10 + C3b * s11;

        acc0 = __builtin_amdgcn_mfma_f32_16x16x32_f16(a0, b00, acc0, 0, 0, 0);
        acc1 = __builtin_amdgcn_mfma_f32_16x16x32_f16(a0, b01, acc1, 0, 0, 0);
        acc2 = __builtin_amdgcn_mfma_f32_16x16x32_f16(a0, b02, acc2, 0, 0, 0);
        acc3 = __builtin_amdgcn_mfma_f32_16x16x32_f16(a0, b03, acc3, 0, 0, 0);
        acc0 = __builtin_amdgcn_mfma_f32_16x16x32_f16(a1, b10, acc0, 0, 0, 0);
        acc1 = __builtin_amdgcn_mfma_f32_16x16x32_f16(a1, b11, acc1, 0, 0, 0);
        acc2 = __builtin_amdgcn_mfma_f32_16x16x32_f16(a1, b12, acc2, 0, 0, 0);
        acc3 = __builtin_amdgcn_mfma_f32_16x16x32_f16(a1, b13, acc3, 0, 0, 0);
    }

    // ---- epilogue: NONTEMPORAL f32x4 stores (lane holds 4 consecutive pixels per o) ----
    {
        int ocol = lane & 15;
        int pixA = wo0 + wl * 16 + khalf * 4;
        float* ob = out + ((size_t)b * COUT) * HW + ho * WW;
        __builtin_nontemporal_store(acc0, (f32x4*)(ob + (size_t)(0 * 16 + ocol) * HW + pixA));
        __builtin_nontemporal_store(acc1, (f32x4*)(ob + (size_t)(1 * 16 + ocol) * HW + pixA));
        __builtin_nontemporal_store(acc2, (f32x4*)(ob + (size_t)(2 * 16 + ocol) * HW + pixA));
        __builtin_nontemporal_store(acc3, (f32x4*)(ob + (size_t)(3 * 16 + ocol) * HW + pixA));
    }
}

extern "C" void kernel_launch(void* const* d_in, const int* in_sizes, int n_in,
                              void* d_out, int out_size, void* d_ws, size_t ws_size,
                              hipStream_t stream)
{
    const float* x    = (const float*)d_in[0];
    const float* woff = (const float*)d_in[1];
    const float* wdef = (const float*)d_in[2];
    float* out  = (float*)d_out;

    unsigned short* wfrag = (unsigned short*)d_ws;          // 73.7 KB
    unsigned short* wfo   = wfrag + 36864;                  // 36.9 KB
    unsigned short* xT    = wfo + 18432;                    // 16.8 MB

    hipLaunchKernelGGL(to_chlast_k, dim3(BATCH * HH), dim3(256), 0, stream,
                       x, xT);
    hipLaunchKernelGGL(build_w_k, dim3((36864 + 18432 + 255) / 256), dim3(256), 0, stream,
                       wdef, woff, wfrag, wfo);
    hipLaunchKernelGGL(deform_fusedE_k, dim3((HH / 8) * 4 * 8), dim3(1024), 0, stream,
                       xT, (const half8*)wfo, (const half8*)wfrag, out);
}

// Round 25
// 53.462 us; speedup vs baseline: 1.0160x; 1.0160x over previous
//
#include <hip/hip_runtime.h>
#include <hip/hip_bf16.h>

#define BATCH 8
#define CIN   64
#define COUT  64
#define HH    128
#define WW    128
#define HW    (HH * WW)
#define OFFC  18
#define KK    9
#define NROWS 9
#define SPX   36                  // staged columns: 32 + 2 halo each side
#define ROWB2 (SPX * 128)         // 4608 B per staged row

typedef __attribute__((ext_vector_type(8))) _Float16 half8;
typedef __attribute__((ext_vector_type(8))) unsigned short ushort8;
typedef __attribute__((ext_vector_type(4))) float f32x4;

__device__ __forceinline__ unsigned short f2hbits(float v) {
    _Float16 h = (_Float16)v;
    return __builtin_bit_cast(unsigned short, h);
}
__device__ __forceinline__ half8 splat8(float f) {
    _Float16 h = (_Float16)f;
    return (half8){h, h, h, h, h, h, h, h};
}

// ------- Kernel X: x (b,c,h,w) f32 -> xT (b,h,w,c) f16 -------
__global__ __launch_bounds__(256) void to_chlast_k(
    const float* __restrict__ x, unsigned short* __restrict__ xT)
{
    __shared__ unsigned short t[128 * 72];
    int blk = blockIdx.x;                    // ho*8 + b
    int b  = blk & 7;
    int ho = blk >> 3;
    int tid = threadIdx.x;

    const float* xr = x + (size_t)b * CIN * HW + ho * WW;
    for (int i = tid; i < 2048; i += 256) {
        int c = i >> 5, w4 = (i & 31) * 4;
        float4 v = *(const float4*)(xr + (size_t)c * HW + w4);
        t[(w4 + 0) * 72 + c] = f2hbits(v.x);
        t[(w4 + 1) * 72 + c] = f2hbits(v.y);
        t[(w4 + 2) * 72 + c] = f2hbits(v.z);
        t[(w4 + 3) * 72 + c] = f2hbits(v.w);
    }
    __syncthreads();

    unsigned short* orow = xT + (size_t)(b * HH + ho) * WW * 64;
    for (int j = tid; j < 1024; j += 256) {
        int w = j >> 3, c8 = (j & 7) * 8;
        *(ushort8*)(orow + w * 64 + c8) = *(const ushort8*)(t + w * 72 + c8);
    }
}

// ------- Kernel B (merged): w_deform -> wf frags; w_offset -> wfo frags (f16) -------
__global__ __launch_bounds__(256) void build_w_k(
    const float* __restrict__ wd, const float* __restrict__ wo,
    unsigned short* __restrict__ wf, unsigned short* __restrict__ wfo)
{
    int idx = blockIdx.x * 256 + threadIdx.x;
    if (idx < 36864) {                               // wf: o*576 + ck
        int ck = idx % 576;
        int o  = idx / 576;
        int c = ck & 63, k = ck >> 6;
        float v = wd[o * 576 + c * 9 + k];
        int kk = ck >> 5, nt = o >> 4;
        int lane = (o & 15) | (((ck >> 3) & 3) << 4);
        int j = ck & 7;
        wf[((kk * 4 + nt) * 64 + lane) * 8 + j] = f2hbits(v);
    } else if (idx < 36864 + 18432) {                // wfo: ov*576 + ck, N pad 18->32
        int i2 = idx - 36864;
        int ck = i2 % 576;
        int ov = i2 / 576;
        int c = ck & 63, tap = ck >> 6;
        float v = (ov < OFFC) ? wo[ov * 576 + c * 9 + tap] : 0.f;
        int kk = ck >> 5, nt = ov >> 4;
        int lane = (ov & 15) | (((ck >> 3) & 3) << 4);
        int j = ck & 7;
        wfo[((kk * 2 + nt) * 64 + lane) * 8 + j] = f2hbits(v);
    }
}

// ---------- Kernel C: LDS-staged gather, 4-row x 32-px / 512-thr, 3 blocks/CU ----------
// SESSION-BEST configuration (R23, 53.55us total). Stage = 9 rows x 36 cols =
// 41.5KB + offsL 10KB = 51.7KB -> 3 blocks/CU -> 6 waves/SIMD. TLP axis fully
// characterized: 2->4 waves/SIMD +3.5%, 4->6 +4%, 6->8 -1.5% (R24) -> 6 is the
// optimum. Datapath: fused MFMA offsets-conv from the stage, inline positions,
// LDS ds_read_b128 gathers (XOR-swizzled), packed-f16 interp (result IS the MFMA
// fragment), pre-masked bilinear weights, bit-identical global fallback for
// out-of-stage corners, direct MFMA-layout nontemporal stores.
__global__ __launch_bounds__(512, 4) void deform_fusedD_k(
    const unsigned short* __restrict__ xT,
    const half8* __restrict__ wfo,
    const half8* __restrict__ wf, float* __restrict__ out)
{
    __shared__ char  stage[NROWS * ROWB2];  // 41472 B
    __shared__ float offsL[8][16 * 20];     // 10240 B  (total 51712 B)

    int tid  = threadIdx.x;
    int blk  = blockIdx.x;                  // (quad*4+wseg)*8 + b
    int b    = blk & 7;
    int t2   = blk >> 3;
    int wseg = t2 & 3;
    int ho0  = (t2 >> 2) * 4;               // 4 rows per block
    int row_lo = ho0 - 2;                   // staged rows row_lo .. row_lo+8
    int wo0  = wseg * 32;
    int col_lo = wo0 - 2;                   // staged cols col_lo .. col_lo+35

    const unsigned short* pT = xT + (size_t)b * HW * 64;

    int lane  = tid & 63;
    int wave  = tid >> 6;                   // 0..7
    int wl    = wave & 1;                   // px half
    int ho    = ho0 + (wave >> 1);          // this wave's output row (4 rows x 2 halves)
    int prow  = lane & 15;
    int khalf = lane >> 4;
    int px    = wo0 + wl * 16 + prow;       // this lane's pixel (absolute)

    // ---- STAGE: 9 rows x 36 cols of xT[b] -> swizzled LDS (512 threads) ----
    for (int c = tid; c < NROWS * SPX * 8; c += 512) {
        int r    = c / (SPX * 8);
        int rem  = c - r * (SPX * 8);
        int xs   = rem >> 3;
        int slot = rem & 7;
        int ar = row_lo + r, ac = col_lo + xs;
        if ((unsigned)ar < (unsigned)HH && (unsigned)ac < (unsigned)WW) {
            ushort8 v = *(const ushort8*)(pT + (((size_t)ar * WW + ac) << 6) + slot * 8);
            *(ushort8*)(stage + r * ROWB2 + xs * 128 + ((slot ^ (xs & 7)) << 4)) = v;
        }
    }
    __syncthreads();

    auto LRD = [&](int r, int xs, int slot) -> half8 {
        return *(const half8*)(stage + r * ROWB2 + xs * 128 + ((slot ^ (xs & 7)) << 4));
    };
    auto GRD = [&](int idx, int h) -> half8 {
        return *(const half8*)(pT + ((size_t)idx << 6) + (khalf << 3) + h * 32);
    };

    // ---- phase A: offsets conv via MFMA (f16) from the stage ----
    {
        f32x4 oa0 = {0.f,0.f,0.f,0.f}, oa1 = {0.f,0.f,0.f,0.f};
        #pragma unroll
        for (int kk = 0; kk < 18; ++kk) {
            int tap = kk >> 1;
            int y   = ho + tap / 3 - 1;            // in [ho0-1, ho0+4], always staged
            int dx  = tap % 3 - 1;
            int slot = khalf + (kk & 1) * 4;
            half8 a0 = {0,0,0,0,0,0,0,0};
            int xw = px + dx;
            if ((unsigned)y < HH && (unsigned)xw < WW) {
                a0 = LRD(y - row_lo, xw - col_lo, slot);   // ry in [1,6], xs in [1,34]
            }
            half8 b0 = wfo[(kk * 2 + 0) * 64 + lane];
            half8 b1 = wfo[(kk * 2 + 1) * 64 + lane];
            oa0 = __builtin_amdgcn_mfma_f32_16x16x32_f16(a0, b0, oa0, 0, 0, 0);
            oa1 = __builtin_amdgcn_mfma_f32_16x16x32_f16(a0, b1, oa1, 0, 0, 0);
        }
        int ocol = lane & 15;
        int pl0  = khalf * 4;
        #pragma unroll
        for (int r = 0; r < 4; ++r)
            offsL[wave][(pl0 + r) * 20 + ocol] = oa0[r];
        if (ocol < 2) {
            #pragma unroll
            for (int r = 0; r < 4; ++r)
                offsL[wave][(pl0 + r) * 20 + 16 + ocol] = oa1[r];
        }
    }
    // no barrier: offsL slice is wave-private

    // ---- tap loop: inline positions + LDS gather + packed-f16 interp + MFMA ----
    f32x4 acc0 = {0.f,0.f,0.f,0.f}, acc1 = {0.f,0.f,0.f,0.f};
    f32x4 acc2 = {0.f,0.f,0.f,0.f}, acc3 = {0.f,0.f,0.f,0.f};

    #pragma unroll
    for (int t = 0; t < 9; ++t) {
        half8 b00 = wf[((2 * t) * 4 + 0) * 64 + lane];
        half8 b01 = wf[((2 * t) * 4 + 1) * 64 + lane];
        half8 b02 = wf[((2 * t) * 4 + 2) * 64 + lane];
        half8 b03 = wf[((2 * t) * 4 + 3) * 64 + lane];
        half8 b10 = wf[((2 * t + 1) * 4 + 0) * 64 + lane];
        half8 b11 = wf[((2 * t + 1) * 4 + 1) * 64 + lane];
        half8 b12 = wf[((2 * t + 1) * 4 + 2) * 64 + lane];
        half8 b13 = wf[((2 * t + 1) * 4 + 3) * 64 + lane];

        // ---------- positions ----------
        float dy = offsL[wave][prow * 20 + 2 * t];
        float dx = offsL[wave][prow * 20 + 2 * t + 1];
        float yy = (float)(ho - 1 + t / 3) + dy;
        float xx = (float)(px - 1 + t % 3) + dx;
        float y0 = floorf(yy), x0 = floorf(xx);
        float wy1 = yy - y0, wx1 = xx - x0;
        float wy0 = 1.f - wy1, wx0 = 1.f - wx1;
        bool vv = (yy > -1.f) && (yy < (float)HH) && (xx > -1.f) && (xx < (float)WW);
        int y0i = (int)y0, x0i = (int)x0;
        bool iy0 = (unsigned)y0i < HH, iy1 = (unsigned)(y0i + 1) < HH;
        bool ix0 = (unsigned)x0i < WW, ix1 = (unsigned)(x0i + 1) < WW;
        float w00 = wy0 * wx0 * ((vv && iy0 && ix0) ? 1.f : 0.f);
        float w01 = wy0 * wx1 * ((vv && iy0 && ix1) ? 1.f : 0.f);
        float w10 = wy1 * wx0 * ((vv && iy1 && ix0) ? 1.f : 0.f);
        float w11 = wy1 * wx1 * ((vv && iy1 && ix1) ? 1.f : 0.f);
        int yc0 = min(max(y0i, 0), HH - 1), yc1 = min(max(y0i + 1, 0), HH - 1);
        int xc0 = min(max(x0i, 0), WW - 1), xc1 = min(max(x0i + 1, 0), WW - 1);

        // ---------- stage coords + in-stage tests ----------
        int ry0 = yc0 - row_lo, ry1 = yc1 - row_lo;
        int xs0 = xc0 - col_lo, xs1 = xc1 - col_lo;
        int r0 = min(max(ry0, 0), NROWS - 1), r1 = min(max(ry1, 0), NROWS - 1);
        int s0 = min(max(xs0, 0), SPX - 1),   s1 = min(max(xs1, 0), SPX - 1);
        bool colOOT = ((unsigned)xs0 >= (unsigned)SPX) || ((unsigned)xs1 >= (unsigned)SPX);
        bool bad0 = ((unsigned)ry0 >= (unsigned)NROWS) || colOOT;
        bool bad1 = ((unsigned)ry1 >= (unsigned)NROWS) || colOOT;

        // ---------- LDS gathers (ds_read_b128) ----------
        half8 C0a = LRD(r0, s0, khalf),     C0b = LRD(r0, s0, khalf + 4);
        half8 C1a = LRD(r0, s1, khalf),     C1b = LRD(r0, s1, khalf + 4);
        half8 C2a = LRD(r1, s0, khalf),     C2b = LRD(r1, s0, khalf + 4);
        half8 C3a = LRD(r1, s1, khalf),     C3b = LRD(r1, s1, khalf + 4);

        // ---------- rare out-of-stage fallbacks (same bytes from global) ----------
        if (bad0) {
            C0a = GRD(yc0 * WW + xc0, 0);  C0b = GRD(yc0 * WW + xc0, 1);
            C1a = GRD(yc0 * WW + xc1, 0);  C1b = GRD(yc0 * WW + xc1, 1);
        }
        if (bad1) {
            C2a = GRD(yc1 * WW + xc0, 0);  C2b = GRD(yc1 * WW + xc0, 1);
            C3a = GRD(yc1 * WW + xc1, 0);  C3b = GRD(yc1 * WW + xc1, 1);
        }

        // ---------- packed-f16 interp: result IS the MFMA fragment ----------
        half8 s00 = splat8(w00), s01 = splat8(w01), s10 = splat8(w10), s11 = splat8(w11);
        half8 a0 = C0a * s00 + C1a * s01 + C2a * s10 + C3a * s11;
        half8 a1 = C0b * s00 + C1b * s01 + C2b * s10 + C3b * s11;

        acc0 = __builtin_amdgcn_mfma_f32_16x16x32_f16(a0, b00, acc0, 0, 0, 0);
        acc1 = __builtin_amdgcn_mfma_f32_16x16x32_f16(a0, b01, acc1, 0, 0, 0);
        acc2 = __builtin_amdgcn_mfma_f32_16x16x32_f16(a0, b02, acc2, 0, 0, 0);
        acc3 = __builtin_amdgcn_mfma_f32_16x16x32_f16(a0, b03, acc3, 0, 0, 0);
        acc0 = __builtin_amdgcn_mfma_f32_16x16x32_f16(a1, b10, acc0, 0, 0, 0);
        acc1 = __builtin_amdgcn_mfma_f32_16x16x32_f16(a1, b11, acc1, 0, 0, 0);
        acc2 = __builtin_amdgcn_mfma_f32_16x16x32_f16(a1, b12, acc2, 0, 0, 0);
        acc3 = __builtin_amdgcn_mfma_f32_16x16x32_f16(a1, b13, acc3, 0, 0, 0);
    }

    // ---- epilogue: NONTEMPORAL f32x4 stores (lane holds 4 consecutive pixels per o) ----
    {
        int ocol = lane & 15;
        int pixA = wo0 + wl * 16 + khalf * 4;
        float* ob = out + ((size_t)b * COUT) * HW + ho * WW;
        __builtin_nontemporal_store(acc0, (f32x4*)(ob + (size_t)(0 * 16 + ocol) * HW + pixA));
        __builtin_nontemporal_store(acc1, (f32x4*)(ob + (size_t)(1 * 16 + ocol) * HW + pixA));
        __builtin_nontemporal_store(acc2, (f32x4*)(ob + (size_t)(2 * 16 + ocol) * HW + pixA));
        __builtin_nontemporal_store(acc3, (f32x4*)(ob + (size_t)(3 * 16 + ocol) * HW + pixA));
    }
}

extern "C" void kernel_launch(void* const* d_in, const int* in_sizes, int n_in,
                              void* d_out, int out_size, void* d_ws, size_t ws_size,
                              hipStream_t stream)
{
    const float* x    = (const float*)d_in[0];
    const float* woff = (const float*)d_in[1];
    const float* wdef = (const float*)d_in[2];
    float* out  = (float*)d_out;

    unsigned short* wfrag = (unsigned short*)d_ws;          // 73.7 KB
    unsigned short* wfo   = wfrag + 36864;                  // 36.9 KB
    unsigned short* xT    = wfo + 18432;                    // 16.8 MB

    hipLaunchKernelGGL(to_chlast_k, dim3(BATCH * HH), dim3(256), 0, stream,
                       x, xT);
    hipLaunchKernelGGL(build_w_k, dim3((36864 + 18432 + 255) / 256), dim3(256), 0, stream,
                       wdef, woff, wfrag, wfo);
    hipLaunchKernelGGL(deform_fusedD_k, dim3((HH / 4) * 4 * 8), dim3(512), 0, stream,
                       xT, (const half8*)wfo, (const half8*)wfrag, out);
}